// Round 14
// baseline (1258.938 us; speedup 1.0000x reference)
//
#include <hip/hip_runtime.h>
#include <math.h>

// SymmetricKMeans on MI355X — R13.
// R12 counters: T~=40 iters; A-phase straggled by 320-blocks-on-256-CUs
// double-occupancy (pub tree waits on slowest group every iter); FPS step
// latency dominated by 7 dependent ds_bpermute shuffles + 16-deep scan.
// Fixes (ALL trajectory arithmetic bitwise-unchanged from R10/R11/R12):
//  - FPS: float4 LDS, depth-4 adjacent-pair tree scan, packed-u64 (val,
//    1023-idx) xor-butterfly all-reduce (exact max-val/min-idx, no bcast)
//  - kmeans: 240 blocks = 3/group x 768 thr (1 block/CU, no stragglers);
//    A: 2 threads/point, 256 cents each, LDS lex merge (first-index exact);
//    lbar3; u16 labels; pub-tree supers = rep XCD (b&7) for local atomics

#define NGRP   80
#define NPTS   1024
#define NCTR   512
#define MAXIT  300
#define KBLK   240
#define KTHR   768
#define NSUP   8
#define OUT_CENT  81920
#define OUT_SCORE 204800

typedef unsigned long long u64;

__device__ float4         g_cent[NGRP * NCTR];
__device__ unsigned short g_cls16[NGRP * NPTS];
__device__ unsigned       g_lbar[NGRP * 32];   // per-group line {cnt,gen}
__device__ unsigned       g_sup[NSUP * 32];    // packed cnt<<16 | conv
__device__ unsigned       g_root[32];
__device__ unsigned       g_pub[32];           // ((it+1)&0xFFFF) | allconv<<31

// ---------------- threefry2x32 (JAX partitionable path) ----------------
__device__ __forceinline__ void tf2x32(unsigned k0, unsigned k1,
                                       unsigned x0, unsigned x1,
                                       unsigned &o0, unsigned &o1) {
  unsigned ks2 = k0 ^ k1 ^ 0x1BD11BDAu;
#define RND(r) { x0 += x1; x1 = (x1 << (r)) | (x1 >> (32 - (r))); x1 ^= x0; }
  x0 += k0; x1 += k1;
  RND(13) RND(15) RND(26) RND(6)
  x0 += k1;  x1 += ks2 + 1u;
  RND(17) RND(29) RND(16) RND(24)
  x0 += ks2; x1 += k0 + 2u;
  RND(13) RND(15) RND(26) RND(6)
  x0 += k0;  x1 += k1 + 3u;
  RND(17) RND(29) RND(16) RND(24)
  x0 += k1;  x1 += ks2 + 4u;
  RND(13) RND(15) RND(26) RND(6)
  x0 += ks2; x1 += k0 + 5u;
#undef RND
  o0 = x0; o1 = x1;
}

// ---------------- FPS: one wave per group ----------------
__global__ __launch_bounds__(64) void fps_kernel(const float *__restrict__ pos) {
  const int g = blockIdx.x, t = threadIdx.x;
  const int e = g & 7;
  __shared__ float4 spt[NPTS];
  if (g == 0) {  // re-init kmeans sync state every launch (graph-safe)
    for (int k = t; k < NGRP * 32; k += 64) g_lbar[k] = 0u;
    for (int k = t; k < NSUP * 32; k += 64) g_sup[k] = 0u;
    if (t == 0) { g_root[0] = 0u; g_pub[0] = 0u; }
  }
  unsigned s0, s1, o0, o1;
  tf2x32(0u, 1u, 0u, 1u, s0, s1);
  tf2x32(s0, s1, 0u, (unsigned)g, o0, o1);
  int last = (int)((o0 ^ o1) & 1023u);

  const float *p = pos + (size_t)e * NPTS * 3;
  float x[16], y[16], z[16], md[16];
#pragma unroll
  for (int k = 0; k < 16; ++k) {
    int n = k * 64 + t;
    x[k] = p[n * 3 + 0]; y[k] = p[n * 3 + 1]; z[k] = p[n * 3 + 2];
    spt[n] = make_float4(x[k], y[k], z[k], 0.0f);
    md[k] = __int_as_float(0x7f800000);
  }
  __syncthreads();
  for (int j = 0; j < NCTR; ++j) {
    const float4 L = spt[last];
    if (t == 0) {   // centroid j = p[last]; c2 plain chain (unchanged)
      float c2 = __fadd_rn(__fadd_rn(__fmul_rn(L.x, L.x), __fmul_rn(L.y, L.y)),
                           __fmul_rn(L.z, L.z));
      g_cent[(size_t)g * NCTR + j] = make_float4(L.x, L.y, L.z, c2);
    }
    float tv[16]; int ti[16];
#pragma unroll
    for (int k = 0; k < 16; ++k) {
      const float dx = __fsub_rn(x[k], L.x), dy = __fsub_rn(y[k], L.y),
                  dz = __fsub_rn(z[k], L.z);
      const float d = __fadd_rn(__fadd_rn(__fmul_rn(dx, dx), __fmul_rn(dy, dy)),
                                __fmul_rn(dz, dz));
      md[k] = fminf(md[k], d);
      tv[k] = md[k]; ti[k] = k * 64 + t;
    }
    // adjacent-pair tree: ranges stay index-ordered => strict > is tie-exact
#pragma unroll
    for (int n2 = 16; n2 > 1; n2 >>= 1)
#pragma unroll
      for (int k = 0; k < 16; ++k) {   // only k < n2/2 active
        if (k < n2 / 2) {
          if (tv[2 * k + 1] > tv[2 * k]) { tv[k] = tv[2 * k + 1]; ti[k] = ti[2 * k + 1]; }
          else                           { tv[k] = tv[2 * k];     ti[k] = ti[2 * k]; }
        }
      }
    // packed (val, 1023-idx): u64 max == (max val, min idx)
    u64 pk = ((u64)__float_as_uint(tv[0]) << 32) | (unsigned)(1023 - ti[0]);
#pragma unroll
    for (int mask = 1; mask < 64; mask <<= 1) {
      u64 o = __shfl_xor(pk, mask, 64);
      if (o > pk) pk = o;
    }
    last = 1023 - (int)(pk & 1023u);
  }
}

// ---------------- per-group 3-block barrier ----------------
__device__ __forceinline__ void lbar3(int grp) {
  __threadfence();
  __syncthreads();
  if (threadIdx.x == 0) {
    unsigned *cp = &g_lbar[grp * 32], *gp = &g_lbar[grp * 32 + 1];
    unsigned gen = __hip_atomic_load(gp, __ATOMIC_RELAXED, __HIP_MEMORY_SCOPE_AGENT);
    unsigned c = __hip_atomic_fetch_add(cp, 1u, __ATOMIC_ACQ_REL, __HIP_MEMORY_SCOPE_AGENT);
    if (c == 2u) {
      __hip_atomic_store(cp, 0u, __ATOMIC_RELAXED, __HIP_MEMORY_SCOPE_AGENT);
      __hip_atomic_fetch_add(gp, 1u, __ATOMIC_ACQ_REL, __HIP_MEMORY_SCOPE_AGENT);
    } else {
      long long guard = 0;
      while (__hip_atomic_load(gp, __ATOMIC_ACQUIRE, __HIP_MEMORY_SCOPE_AGENT) == gen) {
        __builtin_amdgcn_s_sleep(1);
        if (++guard > (1ll << 24)) break;  // safety valve
      }
    }
  }
  __syncthreads();
  __threadfence();
}

// ---------------- persistent k-means: 3 blocks/group, 768 thr ----------------
__global__ __launch_bounds__(KTHR) void kmeans_kernel(
    const float *__restrict__ pos, float *__restrict__ out) {
  const int b = blockIdx.x, t = threadIdx.x;
  const int g = b / 3, q = b - 3 * g;
  const int e = g & 7;
  const int NP   = (q == 0) ? 342 : 341;
  const int base = (q == 0) ? 0 : 342 + (q - 1) * 341;
  const bool isRep = (q == 0);
  const int lane = t & 63, wv = t >> 6;   // wv < 12

  __shared__ float4 scent[NCTR];
  __shared__ float  spx[NPTS], spy[NPTS], spz[NPTS];
  __shared__ int    slab[NPTS];
  __shared__ int    cnt[NCTR], offs[NCTR];
  __shared__ int    idx[NPTS];
  __shared__ float  hv[352];
  __shared__ int    hi[352];
  __shared__ float  redf[12];
  __shared__ double redd[12];
  __shared__ unsigned s_pub;

  {
    const float *gp = pos + (size_t)e * NPTS * 3;
    for (int k = t; k < NPTS; k += KTHR) {
      spx[k] = gp[3 * k]; spy[k] = gp[3 * k + 1]; spz[k] = gp[3 * k + 2];
    }
    for (int k = t; k < NCTR; k += KTHR) scent[k] = g_cent[(size_t)g * NCTR + k];
  }
  __syncthreads();

  const bool loA = (t < NP);
  const bool hiA = (t >= 384 && t < 384 + NP);
  const int pt = loA ? t : (hiA ? t - 384 : 0);
  const int pn = base + pt;                       // point in group
  const float px = spx[pn], py = spy[pn], pz = spz[pn];
  const float p2 = __fadd_rn(__fadd_rn(__fmul_rn(px, px), __fmul_rn(py, py)),
                             __fmul_rn(pz, pz));
  const int cbase = hiA ? 256 : 0;

  int mycls = 0;
  for (int it = 0; it < MAXIT; ++it) {
    // ---- phase A: each half-thread scans 256 cents, stripe-4 ----
    float best = __int_as_float(0x7f800000); int bm = cbase;
    if (loA || hiA) {
      float b0 = best, b1 = best, b2 = best, b3 = best;
      int i0 = 0, i1 = 0, i2 = 0, i3 = 0;
#pragma unroll 2
      for (int i = 0; i < 64; ++i) {
        float4 c0 = scent[cbase + i],       c1 = scent[cbase + 64 + i],
               c2 = scent[cbase + 128 + i], c3 = scent[cbase + 192 + i];
        float d0 = __fadd_rn(__fsub_rn(p2, __fmul_rn(2.0f,
                      fmaf(pz, c0.z, fmaf(py, c0.y, __fmul_rn(px, c0.x))))), c0.w);
        float d1 = __fadd_rn(__fsub_rn(p2, __fmul_rn(2.0f,
                      fmaf(pz, c1.z, fmaf(py, c1.y, __fmul_rn(px, c1.x))))), c1.w);
        float d2 = __fadd_rn(__fsub_rn(p2, __fmul_rn(2.0f,
                      fmaf(pz, c2.z, fmaf(py, c2.y, __fmul_rn(px, c2.x))))), c2.w);
        float d3 = __fadd_rn(__fsub_rn(p2, __fmul_rn(2.0f,
                      fmaf(pz, c3.z, fmaf(py, c3.y, __fmul_rn(px, c3.x))))), c3.w);
        if (d0 < b0) { b0 = d0; i0 = i; }
        if (d1 < b1) { b1 = d1; i1 = i; }
        if (d2 < b2) { b2 = d2; i2 = i; }
        if (d3 < b3) { b3 = d3; i3 = i; }
      }
      best = b0; bm = cbase + i0;                     // ascending stripe bases:
      if (b1 < best) { best = b1; bm = cbase + 64 + i1; }   // strict < = first idx
      if (b2 < best) { best = b2; bm = cbase + 128 + i2; }
      if (b3 < best) { best = b3; bm = cbase + 192 + i3; }
    }
    if (hiA) { hv[pt] = best; hi[pt] = bm; }
    __syncthreads();
    if (loA) {
      if (hv[pt] < best) { best = hv[pt]; bm = hi[pt]; }  // ties keep low half
      g_cls16[(size_t)g * NPTS + pn] = (unsigned short)bm;
      mycls = bm;
    }
    lbar3(g);

    // ---- phase B (replicated x3): CSR + ascending-point-order sums ----
    for (int k = t; k < NPTS; k += KTHR) slab[k] = (int)g_cls16[(size_t)g * NPTS + k];
    if (t < NCTR) cnt[t] = 0;
    __syncthreads();
    for (int k = t; k < NPTS; k += KTHR) atomicAdd(&cnt[slab[k]], 1);
    __syncthreads();
    int *src = cnt, *dst = offs;
    for (int d = 1; d < NCTR; d <<= 1) {     // Hillis-Steele inclusive scan
      if (t < NCTR) { int v = src[t]; if (t >= d) v += src[t - d]; dst[t] = v; }
      __syncthreads();
      int *tmp = src; src = dst; dst = tmp;
    }
    int *incl = src, *wctr = dst;
    if (t < NCTR) wctr[t] = 0;
    __syncthreads();
    for (int k = t; k < NPTS; k += KTHR) {
      int c = slab[k];
      int s2 = atomicAdd(&wctr[c], 1);
      idx[(c ? incl[c - 1] : 0) + s2] = k;
    }
    __syncthreads();
    float mx = 0.0f;
    if (t < NCTR) {
      const int c = t;
      const int b2 = c ? incl[c - 1] : 0;
      const int kk = incl[c] - b2;
      for (int i = b2 + 1; i < b2 + kk; ++i) {       // sort ascending
        int v = idx[i], j = i - 1;
        while (j >= b2 && idx[j] > v) { idx[j + 1] = idx[j]; --j; }
        idx[j + 1] = v;
      }
      float4 oldc = scent[c];
      float nx, ny, nz;
      if (kk > 0) {
        float sxx = 0.f, syy = 0.f, szz = 0.f;
        for (int i = 0; i < kk; ++i) {               // same adds, same order
          int n2 = idx[b2 + i];
          sxx = __fadd_rn(sxx, spx[n2]);
          syy = __fadd_rn(syy, spy[n2]);
          szz = __fadd_rn(szz, spz[n2]);
        }
        float fc = (float)kk;
        nx = __fdiv_rn(sxx, fc); ny = __fdiv_rn(syy, fc); nz = __fdiv_rn(szz, fc);
      } else { nx = oldc.x; ny = oldc.y; nz = oldc.z; }
      float dx = __fsub_rn(oldc.x, nx), dy = __fsub_rn(oldc.y, ny),
            dz = __fsub_rn(oldc.z, nz);
      float nr = __fsqrt_rn(__fadd_rn(__fadd_rn(__fmul_rn(dx, dx), __fmul_rn(dy, dy)),
                                      __fmul_rn(dz, dz)));
      if (nr > mx) mx = nr;
      float c2v = __fadd_rn(__fadd_rn(__fmul_rn(nx, nx), __fmul_rn(ny, ny)),
                            __fmul_rn(nz, nz));
      scent[c] = make_float4(nx, ny, nz, c2v);
    }
    for (int off = 32; off; off >>= 1) {
      float o = __shfl_down(mx, off, 64);
      if (o > mx) mx = o;
    }
    if (lane == 0) redf[wv] = mx;
    __syncthreads();

    // ---- convergence tree: 80 reps -> 8 XCD-local supers -> root -> pub ----
    if (t == 0) {
      if (isRep) {
        float bmx = redf[0];
        for (int k = 1; k < 12; ++k) if (redf[k] > bmx) bmx = redf[k];
        unsigned conv = (bmx < 1e-3f) ? 1u : 0u;     // f32 compare (unchanged)
        int s = b & 7;                                // rep's XCD => local L2
        unsigned old = __hip_atomic_fetch_add(&g_sup[s * 32], 0x10000u + conv,
                         __ATOMIC_ACQ_REL, __HIP_MEMORY_SCOPE_AGENT);
        if ((old >> 16) == 9u) {
          unsigned sconv = (((old & 0xFFFFu) + conv) == 10u) ? 1u : 0u;
          __hip_atomic_store(&g_sup[s * 32], 0u, __ATOMIC_RELAXED, __HIP_MEMORY_SCOPE_AGENT);
          unsigned old2 = __hip_atomic_fetch_add(&g_root[0], 0x10000u + sconv,
                            __ATOMIC_ACQ_REL, __HIP_MEMORY_SCOPE_AGENT);
          if ((old2 >> 16) == (unsigned)(NSUP - 1)) {
            unsigned allc = (((old2 & 0xFFFFu) + sconv) == (unsigned)NSUP) ? 1u : 0u;
            __hip_atomic_store(&g_root[0], 0u, __ATOMIC_RELAXED, __HIP_MEMORY_SCOPE_AGENT);
            __hip_atomic_store(&g_pub[0],
                (unsigned)((it + 1) & 0xFFFF) | (allc << 31),
                __ATOMIC_RELEASE, __HIP_MEMORY_SCOPE_AGENT);
          }
        }
      }
      unsigned want = (unsigned)((it + 1) & 0xFFFF);
      unsigned pub; long long guard = 0;
      do {
        pub = __hip_atomic_load(&g_pub[0], __ATOMIC_ACQUIRE, __HIP_MEMORY_SCOPE_AGENT);
        if ((pub & 0xFFFFu) == want) break;
        __builtin_amdgcn_s_sleep(1);
      } while (++guard < (1ll << 24));               // safety valve
      s_pub = pub;
    }
    __syncthreads();
    if (s_pub >> 31) break;
  }

  // ---- outputs (f32 buffer) ----
  if (loA) out[(size_t)g * NPTS + pn] = (float)mycls;   // classification
  if (isRep) {
    if (t < NCTR) {                                     // centroids
      float4 cc = scent[t];
      float *o = out + OUT_CENT + ((size_t)g * NCTR + t) * 3;
      o[0] = cc.x; o[1] = cc.y; o[2] = cc.z;
    }
    double s = 0.0;                                     // score: L1, f64 accum
    for (int k = t; k < NPTS; k += KTHR) {
      float4 cc = scent[slab[k]];
      s += (double)fabsf(__fsub_rn(spx[k], cc.x)) +
           (double)fabsf(__fsub_rn(spy[k], cc.y)) +
           (double)fabsf(__fsub_rn(spz[k], cc.z));
    }
    for (int off = 32; off; off >>= 1) s += __shfl_down(s, off, 64);
    if (lane == 0) redd[wv] = s;
    __syncthreads();
    if (t == 0) {
      double tot = 0.0;
      for (int k = 0; k < 12; ++k) tot += redd[k];
      out[OUT_SCORE + g] = (float)tot;
    }
  }
}

extern "C" void kernel_launch(void *const *d_in, const int *in_sizes, int n_in,
                              void *d_out, int out_size, void *d_ws, size_t ws_size,
                              hipStream_t stream) {
  const float *pos = (const float *)d_in[0];
  float *out = (float *)d_out;
  (void)d_ws; (void)ws_size;

  fps_kernel<<<NGRP, 64, 0, stream>>>(pos);
  kmeans_kernel<<<KBLK, KTHR, 0, stream>>>(pos, out);
}